// Round 7
// baseline (209.063 us; speedup 1.0000x reference)
//
#include <hip/hip_runtime.h>
#include <hip/hip_bf16.h>
#include <math.h>

#define DD 64
#define NSLICE 64          // edge slices; per-slice edges = 12500 (<2^15, u16-safe)
#define SEGH 12800         // nodes per hist segment (u16-packed pairs in LDS)
#define NSEGH 4            // SEGH*NSEGH >= N
#define SEGB 12800         // nodes per bucket segment (int cursors)
#define NSEGB 4

__device__ __forceinline__ int wave_incl_scan(int v, int lane) {
    #pragma unroll
    for (int d = 1; d < 64; d <<= 1) {
        int u = __shfl_up(v, d, 64);
        if (lane >= d) v += u;
    }
    return v;
}

// ---------------- histogram: grid = (slice, segment), packed u16 LDS ------
__global__ __launch_bounds__(256) void hist_kernel(
    const int* __restrict__ src, const int* __restrict__ dst,
    unsigned short* __restrict__ hist_o, unsigned short* __restrict__ hist_i,
    int E, int N)
{
    __shared__ unsigned int ho[SEGH / 2];
    __shared__ unsigned int hi[SEGH / 2];
    int b = blockIdx.x, s = blockIdx.y, t = threadIdx.x;
    int per = (E + NSLICE - 1) / NSLICE;
    int e0 = b * per, e1 = min(E, e0 + per);
    int base = s * SEGH;
    int segn = min(SEGH, N - base);
    if (segn <= 0) return;

    for (int j = t; j < SEGH / 2; j += 256) { ho[j] = 0u; hi[j] = 0u; }
    __syncthreads();

    int eV = e1 & ~3;
    const int4* s4 = (const int4*)src;
    const int4* d4 = (const int4*)dst;
    for (int q = (e0 >> 2) + t; q < (eV >> 2); q += 256) {
        int4 sv = s4[q];
        int4 dv = d4[q];
        unsigned u;
        u = (unsigned)(sv.x - base); if (u < (unsigned)segn) atomicAdd(&ho[u >> 1], 1u << ((u & 1) * 16));
        u = (unsigned)(sv.y - base); if (u < (unsigned)segn) atomicAdd(&ho[u >> 1], 1u << ((u & 1) * 16));
        u = (unsigned)(sv.z - base); if (u < (unsigned)segn) atomicAdd(&ho[u >> 1], 1u << ((u & 1) * 16));
        u = (unsigned)(sv.w - base); if (u < (unsigned)segn) atomicAdd(&ho[u >> 1], 1u << ((u & 1) * 16));
        u = (unsigned)(dv.x - base); if (u < (unsigned)segn) atomicAdd(&hi[u >> 1], 1u << ((u & 1) * 16));
        u = (unsigned)(dv.y - base); if (u < (unsigned)segn) atomicAdd(&hi[u >> 1], 1u << ((u & 1) * 16));
        u = (unsigned)(dv.z - base); if (u < (unsigned)segn) atomicAdd(&hi[u >> 1], 1u << ((u & 1) * 16));
        u = (unsigned)(dv.w - base); if (u < (unsigned)segn) atomicAdd(&hi[u >> 1], 1u << ((u & 1) * 16));
    }
    for (int e = eV + t; e < e1; e += 256) {
        unsigned u;
        u = (unsigned)(src[e] - base); if (u < (unsigned)segn) atomicAdd(&ho[u >> 1], 1u << ((u & 1) * 16));
        u = (unsigned)(dst[e] - base); if (u < (unsigned)segn) atomicAdd(&hi[u >> 1], 1u << ((u & 1) * 16));
    }
    __syncthreads();
    for (int j = t; j < segn; j += 256) {
        unsigned sh = (j & 1) * 16;
        hist_o[(size_t)b * N + base + j] = (unsigned short)((ho[j >> 1] >> sh) & 0xFFFFu);
        hist_i[(size_t)b * N + base + j] = (unsigned short)((hi[j >> 1] >> sh) & 0xFFFFu);
    }
}

// ------ fused reduce + block-level scan ------
__global__ __launch_bounds__(256) void reduce_scan_kernel(
    const unsigned short* __restrict__ hist_o, unsigned short* __restrict__ hist_i,
    int* __restrict__ offs, float* __restrict__ rs_odeg,
    float* __restrict__ rs_ideg, int* __restrict__ bsum, int N)
{
    int t = threadIdx.x, lane = t & 63, wid = t >> 6;
    int d = blockIdx.x * 256 + t;
    int run_o = 0, run_i = 0;
    if (d < N) {
        #pragma unroll 4
        for (int b = 0; b < NSLICE; ++b) {
            run_o += hist_o[(size_t)b * N + d];
            int tv = hist_i[(size_t)b * N + d];
            hist_i[(size_t)b * N + d] = (unsigned short)run_i;  // excl prefix (<=max indeg, fits u16)
            run_i += tv;
        }
    }
    int sv = wave_incl_scan(run_i, lane);
    __shared__ int ws[4], wso[4];
    if (lane == 63) ws[wid] = sv;
    __syncthreads();
    if (t == 0) {
        int a = 0;
        for (int w = 0; w < 4; ++w) { wso[w] = a; a += ws[w]; }
        bsum[blockIdx.x] = a;
    }
    __syncthreads();
    if (d < N) {
        offs[d] = sv - run_i + wso[wid];
        rs_odeg[d] = rsqrtf((float)run_o);   // inf only for never-src (never read)
        rs_ideg[d] = (run_i > 0) ? rsqrtf((float)run_i) : 0.0f;
    }
}

// ------ scan_add: each block self-sums bsum[0..blockIdx) and adds --------
__global__ __launch_bounds__(256) void scan_add_kernel(
    int* __restrict__ offs, const int* __restrict__ bsum, int n)
{
    __shared__ int wsum[4];
    int t = threadIdx.x, lane = t & 63, wid = t >> 6;
    int v = (t < blockIdx.x) ? bsum[t] : 0;    // nb <= 256
    #pragma unroll
    for (int dlt = 32; dlt >= 1; dlt >>= 1) v += __shfl_xor(v, dlt, 64);
    if (lane == 0) wsum[wid] = v;
    __syncthreads();
    int pre = wsum[0] + wsum[1] + wsum[2] + wsum[3];
    int i = blockIdx.x * 256 + t;
    if (i < n) offs[i] += pre;
}

// ---------------- bucket fill: grid = (slice, segment), LDS cursors -------
__global__ __launch_bounds__(256) void bucket_kernel(
    const int* __restrict__ src, const int* __restrict__ dst,
    const int* __restrict__ offs, const unsigned short* __restrict__ hist_i,
    int* __restrict__ sorted_src, int E, int N)
{
    __shared__ int cur[SEGB];
    int b = blockIdx.x, s = blockIdx.y, t = threadIdx.x;
    int per = (E + NSLICE - 1) / NSLICE;
    int e0 = b * per, e1 = min(E, e0 + per);
    int base = s * SEGB;
    int segn = min(SEGB, N - base);
    if (segn <= 0) return;

    for (int j = t; j < segn; j += 256)
        cur[j] = offs[base + j] + (int)hist_i[(size_t)b * N + base + j];
    __syncthreads();

    int eV = e1 & ~3;
    const int4* s4 = (const int4*)src;
    const int4* d4 = (const int4*)dst;
    for (int q = (e0 >> 2) + t; q < (eV >> 2); q += 256) {
        int4 dv = d4[q];
        int4 sv = s4[q];
        unsigned u;
        u = (unsigned)(dv.x - base);
        if (u < (unsigned)segn) sorted_src[atomicAdd(&cur[u], 1)] = sv.x;
        u = (unsigned)(dv.y - base);
        if (u < (unsigned)segn) sorted_src[atomicAdd(&cur[u], 1)] = sv.y;
        u = (unsigned)(dv.z - base);
        if (u < (unsigned)segn) sorted_src[atomicAdd(&cur[u], 1)] = sv.z;
        u = (unsigned)(dv.w - base);
        if (u < (unsigned)segn) sorted_src[atomicAdd(&cur[u], 1)] = sv.w;
    }
    for (int e = eV + t; e < e1; e += 256) {
        unsigned u = (unsigned)(dst[e] - base);
        if (u < (unsigned)segn) sorted_src[atomicAdd(&cur[u], 1)] = src[e];
    }
}

// ---------------- gather: wave per node, 16-edge unroll (4 loads deep) ----
__global__ __launch_bounds__(256) void gather_kernel(
    const float* __restrict__ x,
    const int* __restrict__ sorted_src,
    const int* __restrict__ offs,
    const float* __restrict__ rs_odeg,
    const float* __restrict__ rs_ideg,
    float* __restrict__ out, int N, int E)
{
    __shared__ int   sS[4][68];
    __shared__ float sW[4][68];
    int t = threadIdx.x, lane = t & 63, wid = t >> 6;
    int sub = lane >> 4, c4 = lane & 15;
    int d = blockIdx.x * 4 + wid;
    if (d >= N) return;

    int beg = offs[d];
    int end = (d + 1 < N) ? offs[d + 1] : E;
    int cnt = end - beg;
    int capped = min(cnt, 64);

    int s_l = 0; float w_l = 0.0f;
    if (lane < capped) {
        s_l = sorted_src[beg + lane];
        w_l = rs_odeg[s_l];
    }
    sS[wid][lane] = s_l;
    sW[wid][lane] = w_l;
    if (lane < 4) { sS[wid][64 + lane] = 0; sW[wid][64 + lane] = 0.0f; }

    float4 acc = make_float4(0.f, 0.f, 0.f, 0.f);
    int j = 0;
    for (; j + 16 <= capped; j += 16) {
        int j0 = j + sub, j1 = j + 4 + sub, j2 = j + 8 + sub, j3 = j + 12 + sub;
        int   sA = sS[wid][j0], sB = sS[wid][j1], sC = sS[wid][j2], sD = sS[wid][j3];
        float wA = sW[wid][j0], wB = sW[wid][j1], wC = sW[wid][j2], wD = sW[wid][j3];
        const float4 xa = *(const float4*)&x[(size_t)sA * DD + (c4 << 2)];
        const float4 xb = *(const float4*)&x[(size_t)sB * DD + (c4 << 2)];
        const float4 xc = *(const float4*)&x[(size_t)sC * DD + (c4 << 2)];
        const float4 xd = *(const float4*)&x[(size_t)sD * DD + (c4 << 2)];
        acc.x = fmaf(wA, xa.x, acc.x); acc.y = fmaf(wA, xa.y, acc.y);
        acc.z = fmaf(wA, xa.z, acc.z); acc.w = fmaf(wA, xa.w, acc.w);
        acc.x = fmaf(wB, xb.x, acc.x); acc.y = fmaf(wB, xb.y, acc.y);
        acc.z = fmaf(wB, xb.z, acc.z); acc.w = fmaf(wB, xb.w, acc.w);
        acc.x = fmaf(wC, xc.x, acc.x); acc.y = fmaf(wC, xc.y, acc.y);
        acc.z = fmaf(wC, xc.z, acc.z); acc.w = fmaf(wC, xc.w, acc.w);
        acc.x = fmaf(wD, xd.x, acc.x); acc.y = fmaf(wD, xd.y, acc.y);
        acc.z = fmaf(wD, xd.z, acc.z); acc.w = fmaf(wD, xd.w, acc.w);
    }
    for (; j + 8 <= capped; j += 8) {
        int j0 = j + sub, j1 = j + 4 + sub;
        int   sA = sS[wid][j0], sB = sS[wid][j1];
        float wA = sW[wid][j0], wB = sW[wid][j1];
        const float4 xa = *(const float4*)&x[(size_t)sA * DD + (c4 << 2)];
        const float4 xb = *(const float4*)&x[(size_t)sB * DD + (c4 << 2)];
        acc.x = fmaf(wA, xa.x, acc.x); acc.y = fmaf(wA, xa.y, acc.y);
        acc.z = fmaf(wA, xa.z, acc.z); acc.w = fmaf(wA, xa.w, acc.w);
        acc.x = fmaf(wB, xb.x, acc.x); acc.y = fmaf(wB, xb.y, acc.y);
        acc.z = fmaf(wB, xb.z, acc.z); acc.w = fmaf(wB, xb.w, acc.w);
    }
    for (; j < capped; j += 4) {
        int jj = j + sub;                 // pads [64..67] are zero-weight
        int   s = sS[wid][jj];
        float w = sW[wid][jj];
        const float4 xv = *(const float4*)&x[(size_t)s * DD + (c4 << 2)];
        acc.x = fmaf(w, xv.x, acc.x); acc.y = fmaf(w, xv.y, acc.y);
        acc.z = fmaf(w, xv.z, acc.z); acc.w = fmaf(w, xv.w, acc.w);
    }
    for (int jt = 64 + sub; jt < cnt; jt += 4) {   // rare: degree > 64
        int s = sorted_src[beg + jt];
        float w = rs_odeg[s];
        const float4 xv = *(const float4*)&x[(size_t)s * DD + (c4 << 2)];
        acc.x = fmaf(w, xv.x, acc.x); acc.y = fmaf(w, xv.y, acc.y);
        acc.z = fmaf(w, xv.z, acc.z); acc.w = fmaf(w, xv.w, acc.w);
    }
    acc.x += __shfl_xor(acc.x, 16, 64); acc.x += __shfl_xor(acc.x, 32, 64);
    acc.y += __shfl_xor(acc.y, 16, 64); acc.y += __shfl_xor(acc.y, 32, 64);
    acc.z += __shfl_xor(acc.z, 16, 64); acc.z += __shfl_xor(acc.z, 32, 64);
    acc.w += __shfl_xor(acc.w, 16, 64); acc.w += __shfl_xor(acc.w, 32, 64);

    float nd = rs_ideg[d];
    if (sub == 0) {
        acc.x *= nd; acc.y *= nd; acc.z *= nd; acc.w *= nd;
        *(float4*)&out[(size_t)d * DD + (c4 << 2)] = acc;
    }
}

// ---------------- FFN: thread-per-row, register-resident h/out ----------
// 128 threads = 128 rows/block. Weights via wave-uniform loads (scalar/L1
// broadcast, no LDS). LDS (stride 65, 2-way free) only stages rows for
// coalesced global I/O. Per thread: 8192 FMAs, VALU-bound.
__global__ __launch_bounds__(128) void ffn_kernel(
    float* __restrict__ io,
    const float* __restrict__ w1, const float* __restrict__ b1,
    const float* __restrict__ w2, const float* __restrict__ b2, int n)
{
    __shared__ float sT[128 * 65];
    int t = threadIdx.x;
    int row0 = blockIdx.x * 128;

    // stage 128 rows, coalesced
    #pragma unroll
    for (int q = 0; q < 16; ++q) {
        int idx4 = t + q * 128;          // float4 index in 128x64 tile
        int r = idx4 >> 4;
        int c = (idx4 & 15) << 2;
        int gr = row0 + r;
        float4 v = (gr < n) ? ((const float4*)io)[((size_t)gr * DD + c) >> 2]
                            : make_float4(0.f, 0.f, 0.f, 0.f);
        *(float4*)&sT[r * 65 + c] = v;
    }
    __syncthreads();

    // GEMM1: h = row . W1 + b1   (row from LDS b32, 2-way alias free)
    float h[64];
    #pragma unroll
    for (int c = 0; c < 64; ++c) h[c] = b1[c];
    for (int k = 0; k < 64; ++k) {
        float rv = sT[t * 65 + k];
        const float4* wrow = (const float4*)&w1[k * 64];   // wave-uniform
        #pragma unroll
        for (int q = 0; q < 16; ++q) {
            float4 w = wrow[q];
            h[q*4+0] = fmaf(rv, w.x, h[q*4+0]);
            h[q*4+1] = fmaf(rv, w.y, h[q*4+1]);
            h[q*4+2] = fmaf(rv, w.z, h[q*4+2]);
            h[q*4+3] = fmaf(rv, w.w, h[q*4+3]);
        }
    }
    // exact GELU in registers
    #pragma unroll
    for (int c = 0; c < 64; ++c) {
        float v = h[c];
        h[c] = 0.5f * v * (1.0f + erff(v * 0.70710678118654752f));
    }
    // GEMM2: out = h . W2 + b2  (h fully in registers — no LDS)
    float o[64];
    #pragma unroll
    for (int c = 0; c < 64; ++c) o[c] = b2[c];
    for (int k = 0; k < 64; ++k) {
        float hv = h[k];
        const float4* wrow = (const float4*)&w2[k * 64];   // wave-uniform
        #pragma unroll
        for (int q = 0; q < 16; ++q) {
            float4 w = wrow[q];
            o[q*4+0] = fmaf(hv, w.x, o[q*4+0]);
            o[q*4+1] = fmaf(hv, w.y, o[q*4+1]);
            o[q*4+2] = fmaf(hv, w.z, o[q*4+2]);
            o[q*4+3] = fmaf(hv, w.w, o[q*4+3]);
        }
    }
    // stage out rows to LDS (own row only; no barrier needed before write)
    #pragma unroll
    for (int q = 0; q < 16; ++q)
        *(float4*)&sT[t * 65 + (q << 2)] =
            make_float4(o[q*4+0], o[q*4+1], o[q*4+2], o[q*4+3]);
    __syncthreads();
    // coalesced store
    #pragma unroll
    for (int q = 0; q < 16; ++q) {
        int idx4 = t + q * 128;
        int r = idx4 >> 4;
        int c = (idx4 & 15) << 2;
        int gr = row0 + r;
        if (gr < n)
            ((float4*)io)[((size_t)gr * DD + c) >> 2] = *(const float4*)&sT[r * 65 + c];
    }
}

extern "C" void kernel_launch(void* const* d_in, const int* in_sizes, int n_in,
                              void* d_out, int out_size, void* d_ws, size_t ws_size,
                              hipStream_t stream)
{
    const float* x    = (const float*)d_in[0];
    const int*   esrc = (const int*)d_in[1];
    const int*   edst = (const int*)d_in[2];
    const float* w1   = (const float*)d_in[3];
    const float* b1   = (const float*)d_in[4];
    const float* w2   = (const float*)d_in[5];
    const float* b2   = (const float*)d_in[6];
    float* out = (float*)d_out;

    int N = in_sizes[0] / DD;   // 50000
    int E = in_sizes[1];        // 800000
    int nb = (N + 255) / 256;   // 196

    // workspace layout (all in d_ws, 256 MB)
    int*            offs       = (int*)d_ws;                         // N
    float*          rs_odeg    = (float*)(offs + N);                 // N
    float*          rs_ideg    = rs_odeg + N;                        // N
    int*            bsum       = (int*)(rs_ideg + N);                // 256
    int*            sorted_src = bsum + 256;                         // E
    unsigned short* hist_o     = (unsigned short*)(sorted_src + E);  // NSLICE*N
    unsigned short* hist_i     = hist_o + (size_t)NSLICE * N;        // NSLICE*N

    hist_kernel<<<dim3(NSLICE, NSEGH), 256, 0, stream>>>(esrc, edst, hist_o, hist_i, E, N);
    reduce_scan_kernel<<<nb, 256, 0, stream>>>(hist_o, hist_i, offs, rs_odeg, rs_ideg, bsum, N);
    scan_add_kernel<<<nb, 256, 0, stream>>>(offs, bsum, N);
    bucket_kernel<<<dim3(NSLICE, NSEGB), 256, 0, stream>>>(esrc, edst, offs, hist_i, sorted_src, E, N);
    gather_kernel<<<(N + 3) / 4, 256, 0, stream>>>(x, sorted_src, offs, rs_odeg, rs_ideg, out, N, E);
    ffn_kernel<<<(N + 127) / 128, 128, 0, stream>>>(out, w1, b1, w2, b2, N);
}

// Round 8
// 182.586 us; speedup vs baseline: 1.1450x; 1.1450x over previous
//
#include <hip/hip_runtime.h>
#include <hip/hip_bf16.h>
#include <math.h>

#define DD 64
#define NSLICE 64          // edge slices; per-slice edges = 12500 (<2^15, u16-safe)
#define SEG 16768          // nodes per segment; 3 segments cover N=50000
#define NSEG 3

__device__ __forceinline__ int wave_incl_scan(int v, int lane) {
    #pragma unroll
    for (int d = 1; d < 64; d <<= 1) {
        int u = __shfl_up(v, d, 64);
        if (lane >= d) v += u;
    }
    return v;
}

// ---------------- histogram: grid = (slice, segment), packed u16 LDS ------
__global__ __launch_bounds__(256) void hist_kernel(
    const int* __restrict__ src, const int* __restrict__ dst,
    unsigned short* __restrict__ hist_o, unsigned short* __restrict__ hist_i,
    int E, int N)
{
    __shared__ unsigned int ho[SEG / 2];
    __shared__ unsigned int hi[SEG / 2];
    int b = blockIdx.x, s = blockIdx.y, t = threadIdx.x;
    int per = (E + NSLICE - 1) / NSLICE;
    int e0 = b * per, e1 = min(E, e0 + per);
    int base = s * SEG;
    int segn = min(SEG, N - base);
    if (segn <= 0) return;

    for (int j = t; j < SEG / 2; j += 256) { ho[j] = 0u; hi[j] = 0u; }
    __syncthreads();

    int eV = e1 & ~3;
    const int4* s4 = (const int4*)src;
    const int4* d4 = (const int4*)dst;
    for (int q = (e0 >> 2) + t; q < (eV >> 2); q += 256) {
        int4 sv = s4[q];
        int4 dv = d4[q];
        unsigned u;
        u = (unsigned)(sv.x - base); if (u < (unsigned)segn) atomicAdd(&ho[u >> 1], 1u << ((u & 1) * 16));
        u = (unsigned)(sv.y - base); if (u < (unsigned)segn) atomicAdd(&ho[u >> 1], 1u << ((u & 1) * 16));
        u = (unsigned)(sv.z - base); if (u < (unsigned)segn) atomicAdd(&ho[u >> 1], 1u << ((u & 1) * 16));
        u = (unsigned)(sv.w - base); if (u < (unsigned)segn) atomicAdd(&ho[u >> 1], 1u << ((u & 1) * 16));
        u = (unsigned)(dv.x - base); if (u < (unsigned)segn) atomicAdd(&hi[u >> 1], 1u << ((u & 1) * 16));
        u = (unsigned)(dv.y - base); if (u < (unsigned)segn) atomicAdd(&hi[u >> 1], 1u << ((u & 1) * 16));
        u = (unsigned)(dv.z - base); if (u < (unsigned)segn) atomicAdd(&hi[u >> 1], 1u << ((u & 1) * 16));
        u = (unsigned)(dv.w - base); if (u < (unsigned)segn) atomicAdd(&hi[u >> 1], 1u << ((u & 1) * 16));
    }
    for (int e = eV + t; e < e1; e += 256) {
        unsigned u;
        u = (unsigned)(src[e] - base); if (u < (unsigned)segn) atomicAdd(&ho[u >> 1], 1u << ((u & 1) * 16));
        u = (unsigned)(dst[e] - base); if (u < (unsigned)segn) atomicAdd(&hi[u >> 1], 1u << ((u & 1) * 16));
    }
    __syncthreads();
    for (int j = t; j < segn; j += 256) {
        unsigned sh = (j & 1) * 16;
        hist_o[(size_t)b * N + base + j] = (unsigned short)((ho[j >> 1] >> sh) & 0xFFFFu);
        hist_i[(size_t)b * N + base + j] = (unsigned short)((hi[j >> 1] >> sh) & 0xFFFFu);
    }
}

// ------ fused reduce + block-level scan ------
__global__ __launch_bounds__(256) void reduce_scan_kernel(
    const unsigned short* __restrict__ hist_o, unsigned short* __restrict__ hist_i,
    int* __restrict__ offs, float* __restrict__ rs_odeg,
    float* __restrict__ rs_ideg, int* __restrict__ bsum, int N)
{
    int t = threadIdx.x, lane = t & 63, wid = t >> 6;
    int d = blockIdx.x * 256 + t;
    int run_o = 0, run_i = 0;
    if (d < N) {
        #pragma unroll 4
        for (int b = 0; b < NSLICE; ++b) {
            run_o += hist_o[(size_t)b * N + d];
            int tv = hist_i[(size_t)b * N + d];
            hist_i[(size_t)b * N + d] = (unsigned short)run_i;  // excl prefix over slices
            run_i += tv;
        }
    }
    int sv = wave_incl_scan(run_i, lane);
    __shared__ int ws[4], wso[4];
    if (lane == 63) ws[wid] = sv;
    __syncthreads();
    if (t == 0) {
        int a = 0;
        for (int w = 0; w < 4; ++w) { wso[w] = a; a += ws[w]; }
        bsum[blockIdx.x] = a;
    }
    __syncthreads();
    if (d < N) {
        offs[d] = sv - run_i + wso[wid];
        rs_odeg[d] = rsqrtf((float)run_o);   // inf only for never-src (never read)
        rs_ideg[d] = (run_i > 0) ? rsqrtf((float)run_i) : 0.0f;
    }
}

// ------ scan_add ------
__global__ __launch_bounds__(256) void scan_add_kernel(
    int* __restrict__ offs, const int* __restrict__ bsum, int n)
{
    __shared__ int wsum[4];
    int t = threadIdx.x, lane = t & 63, wid = t >> 6;
    int v = (t < blockIdx.x) ? bsum[t] : 0;    // nb <= 256
    #pragma unroll
    for (int dlt = 32; dlt >= 1; dlt >>= 1) v += __shfl_xor(v, dlt, 64);
    if (lane == 0) wsum[wid] = v;
    __syncthreads();
    int pre = wsum[0] + wsum[1] + wsum[2] + wsum[3];
    int i = blockIdx.x * 256 + t;
    if (i < n) offs[i] += pre;
}

// ---------------- bucket fill: grid = (slice, segment), LDS cursors -------
__global__ __launch_bounds__(256) void bucket_kernel(
    const int* __restrict__ src, const int* __restrict__ dst,
    const int* __restrict__ offs, const unsigned short* __restrict__ hist_i,
    int* __restrict__ sorted_src, int E, int N)
{
    __shared__ int cur[SEG];
    int b = blockIdx.x, s = blockIdx.y, t = threadIdx.x;
    int per = (E + NSLICE - 1) / NSLICE;
    int e0 = b * per, e1 = min(E, e0 + per);
    int base = s * SEG;
    int segn = min(SEG, N - base);
    if (segn <= 0) return;

    for (int j = t; j < segn; j += 256)
        cur[j] = offs[base + j] + (int)hist_i[(size_t)b * N + base + j];
    __syncthreads();

    int eV = e1 & ~3;
    const int4* s4 = (const int4*)src;
    const int4* d4 = (const int4*)dst;
    for (int q = (e0 >> 2) + t; q < (eV >> 2); q += 256) {
        int4 dv = d4[q];
        int4 sv = s4[q];
        unsigned u;
        u = (unsigned)(dv.x - base);
        if (u < (unsigned)segn) sorted_src[atomicAdd(&cur[u], 1)] = sv.x;
        u = (unsigned)(dv.y - base);
        if (u < (unsigned)segn) sorted_src[atomicAdd(&cur[u], 1)] = sv.y;
        u = (unsigned)(dv.z - base);
        if (u < (unsigned)segn) sorted_src[atomicAdd(&cur[u], 1)] = sv.z;
        u = (unsigned)(dv.w - base);
        if (u < (unsigned)segn) sorted_src[atomicAdd(&cur[u], 1)] = sv.w;
    }
    for (int e = eV + t; e < e1; e += 256) {
        unsigned u = (unsigned)(dst[e] - base);
        if (u < (unsigned)segn) sorted_src[atomicAdd(&cur[u], 1)] = src[e];
    }
}

// ---------------- gather: wave per node, 16-edge unroll (4 loads deep) ----
__global__ __launch_bounds__(256) void gather_kernel(
    const float* __restrict__ x,
    const int* __restrict__ sorted_src,
    const int* __restrict__ offs,
    const float* __restrict__ rs_odeg,
    const float* __restrict__ rs_ideg,
    float* __restrict__ out, int N, int E)
{
    __shared__ int   sS[4][68];
    __shared__ float sW[4][68];
    int t = threadIdx.x, lane = t & 63, wid = t >> 6;
    int sub = lane >> 4, c4 = lane & 15;
    int d = blockIdx.x * 4 + wid;
    if (d >= N) return;

    int beg = offs[d];
    int end = (d + 1 < N) ? offs[d + 1] : E;
    int cnt = end - beg;
    int capped = min(cnt, 64);

    int s_l = 0; float w_l = 0.0f;
    if (lane < capped) {
        s_l = sorted_src[beg + lane];
        w_l = rs_odeg[s_l];
    }
    sS[wid][lane] = s_l;
    sW[wid][lane] = w_l;
    if (lane < 4) { sS[wid][64 + lane] = 0; sW[wid][64 + lane] = 0.0f; }

    float4 acc = make_float4(0.f, 0.f, 0.f, 0.f);
    int j = 0;
    for (; j + 16 <= capped; j += 16) {
        int j0 = j + sub, j1 = j + 4 + sub, j2 = j + 8 + sub, j3 = j + 12 + sub;
        int   sA = sS[wid][j0], sB = sS[wid][j1], sC = sS[wid][j2], sD = sS[wid][j3];
        float wA = sW[wid][j0], wB = sW[wid][j1], wC = sW[wid][j2], wD = sW[wid][j3];
        const float4 xa = *(const float4*)&x[(size_t)sA * DD + (c4 << 2)];
        const float4 xb = *(const float4*)&x[(size_t)sB * DD + (c4 << 2)];
        const float4 xc = *(const float4*)&x[(size_t)sC * DD + (c4 << 2)];
        const float4 xd = *(const float4*)&x[(size_t)sD * DD + (c4 << 2)];
        acc.x = fmaf(wA, xa.x, acc.x); acc.y = fmaf(wA, xa.y, acc.y);
        acc.z = fmaf(wA, xa.z, acc.z); acc.w = fmaf(wA, xa.w, acc.w);
        acc.x = fmaf(wB, xb.x, acc.x); acc.y = fmaf(wB, xb.y, acc.y);
        acc.z = fmaf(wB, xb.z, acc.z); acc.w = fmaf(wB, xb.w, acc.w);
        acc.x = fmaf(wC, xc.x, acc.x); acc.y = fmaf(wC, xc.y, acc.y);
        acc.z = fmaf(wC, xc.z, acc.z); acc.w = fmaf(wC, xc.w, acc.w);
        acc.x = fmaf(wD, xd.x, acc.x); acc.y = fmaf(wD, xd.y, acc.y);
        acc.z = fmaf(wD, xd.z, acc.z); acc.w = fmaf(wD, xd.w, acc.w);
    }
    for (; j + 8 <= capped; j += 8) {
        int j0 = j + sub, j1 = j + 4 + sub;
        int   sA = sS[wid][j0], sB = sS[wid][j1];
        float wA = sW[wid][j0], wB = sW[wid][j1];
        const float4 xa = *(const float4*)&x[(size_t)sA * DD + (c4 << 2)];
        const float4 xb = *(const float4*)&x[(size_t)sB * DD + (c4 << 2)];
        acc.x = fmaf(wA, xa.x, acc.x); acc.y = fmaf(wA, xa.y, acc.y);
        acc.z = fmaf(wA, xa.z, acc.z); acc.w = fmaf(wA, xa.w, acc.w);
        acc.x = fmaf(wB, xb.x, acc.x); acc.y = fmaf(wB, xb.y, acc.y);
        acc.z = fmaf(wB, xb.z, acc.z); acc.w = fmaf(wB, xb.w, acc.w);
    }
    for (; j < capped; j += 4) {
        int jj = j + sub;                 // pads [64..67] are zero-weight
        int   s = sS[wid][jj];
        float w = sW[wid][jj];
        const float4 xv = *(const float4*)&x[(size_t)s * DD + (c4 << 2)];
        acc.x = fmaf(w, xv.x, acc.x); acc.y = fmaf(w, xv.y, acc.y);
        acc.z = fmaf(w, xv.z, acc.z); acc.w = fmaf(w, xv.w, acc.w);
    }
    for (int jt = 64 + sub; jt < cnt; jt += 4) {   // rare: degree > 64
        int s = sorted_src[beg + jt];
        float w = rs_odeg[s];
        const float4 xv = *(const float4*)&x[(size_t)s * DD + (c4 << 2)];
        acc.x = fmaf(w, xv.x, acc.x); acc.y = fmaf(w, xv.y, acc.y);
        acc.z = fmaf(w, xv.z, acc.z); acc.w = fmaf(w, xv.w, acc.w);
    }
    acc.x += __shfl_xor(acc.x, 16, 64); acc.x += __shfl_xor(acc.x, 32, 64);
    acc.y += __shfl_xor(acc.y, 16, 64); acc.y += __shfl_xor(acc.y, 32, 64);
    acc.z += __shfl_xor(acc.z, 16, 64); acc.z += __shfl_xor(acc.z, 32, 64);
    acc.w += __shfl_xor(acc.w, 16, 64); acc.w += __shfl_xor(acc.w, 32, 64);

    float nd = rs_ideg[d];
    if (sub == 0) {
        acc.x *= nd; acc.y *= nd; acc.z *= nd; acc.w *= nd;
        *(float4*)&out[(size_t)d * DD + (c4 << 2)] = acc;
    }
}

// ---------------- FFN: block=128, 64 rows, 2 rows/thread, LDS weights ----
__global__ __launch_bounds__(128) void ffn_kernel(
    float* __restrict__ io,
    const float* __restrict__ w1, const float* __restrict__ b1,
    const float* __restrict__ w2, const float* __restrict__ b2, int n)
{
    __shared__ float sW1[4096];
    __shared__ float sW2[4096];
    __shared__ float sT[64 * 68];

    int t = threadIdx.x;
    int row0 = blockIdx.x * 64;

    const float4* w1v = (const float4*)w1;
    const float4* w2v = (const float4*)w2;
    #pragma unroll
    for (int q = 0; q < 8; ++q) {
        ((float4*)sW1)[t + q * 128] = w1v[t + q * 128];
        ((float4*)sW2)[t + q * 128] = w2v[t + q * 128];
    }
    #pragma unroll
    for (int q = 0; q < 8; ++q) {
        int idx4 = t + q * 128;          // float4 index in 64x64 tile
        int r = idx4 >> 4;
        int c = (idx4 & 15) << 2;
        int gr = row0 + r;
        float4 v = (gr < n) ? ((const float4*)io)[((size_t)gr * DD + c) >> 2]
                            : make_float4(0.f, 0.f, 0.f, 0.f);
        *(float4*)&sT[r * 68 + c] = v;
    }
    __syncthreads();

    int r0 = t >> 2;          // 0..31
    int r1 = r0 + 32;
    int cb = (t & 3) << 4;

    float a0[16], a1[16];
    #pragma unroll
    for (int j = 0; j < 16; ++j) { float bv = b1[cb + j]; a0[j] = bv; a1[j] = bv; }
    #pragma unroll 4
    for (int k = 0; k < 64; ++k) {
        float rv0 = sT[r0 * 68 + k];
        float rv1 = sT[r1 * 68 + k];
        #pragma unroll
        for (int q = 0; q < 4; ++q) {
            float4 w = *(const float4*)&sW1[k * 64 + cb + (q << 2)];
            a0[q*4+0] = fmaf(rv0, w.x, a0[q*4+0]); a1[q*4+0] = fmaf(rv1, w.x, a1[q*4+0]);
            a0[q*4+1] = fmaf(rv0, w.y, a0[q*4+1]); a1[q*4+1] = fmaf(rv1, w.y, a1[q*4+1]);
            a0[q*4+2] = fmaf(rv0, w.z, a0[q*4+2]); a1[q*4+2] = fmaf(rv1, w.z, a1[q*4+2]);
            a0[q*4+3] = fmaf(rv0, w.w, a0[q*4+3]); a1[q*4+3] = fmaf(rv1, w.w, a1[q*4+3]);
        }
    }
    #pragma unroll
    for (int j = 0; j < 16; ++j) {
        float v0 = a0[j], v1 = a1[j];
        a0[j] = 0.5f * v0 * (1.0f + erff(v0 * 0.70710678118654752f));
        a1[j] = 0.5f * v1 * (1.0f + erff(v1 * 0.70710678118654752f));
    }
    __syncthreads();
    #pragma unroll
    for (int q = 0; q < 4; ++q) {
        *(float4*)&sT[r0 * 68 + cb + (q << 2)] =
            make_float4(a0[q*4+0], a0[q*4+1], a0[q*4+2], a0[q*4+3]);
        *(float4*)&sT[r1 * 68 + cb + (q << 2)] =
            make_float4(a1[q*4+0], a1[q*4+1], a1[q*4+2], a1[q*4+3]);
    }
    __syncthreads();

    #pragma unroll
    for (int j = 0; j < 16; ++j) { float bv = b2[cb + j]; a0[j] = bv; a1[j] = bv; }
    #pragma unroll 4
    for (int k = 0; k < 64; ++k) {
        float hv0 = sT[r0 * 68 + k];
        float hv1 = sT[r1 * 68 + k];
        #pragma unroll
        for (int q = 0; q < 4; ++q) {
            float4 w = *(const float4*)&sW2[k * 64 + cb + (q << 2)];
            a0[q*4+0] = fmaf(hv0, w.x, a0[q*4+0]); a1[q*4+0] = fmaf(hv1, w.x, a1[q*4+0]);
            a0[q*4+1] = fmaf(hv0, w.y, a0[q*4+1]); a1[q*4+1] = fmaf(hv1, w.y, a1[q*4+1]);
            a0[q*4+2] = fmaf(hv0, w.z, a0[q*4+2]); a1[q*4+2] = fmaf(hv1, w.z, a1[q*4+2]);
            a0[q*4+3] = fmaf(hv0, w.w, a0[q*4+3]); a1[q*4+3] = fmaf(hv1, w.w, a1[q*4+3]);
        }
    }
    int g0 = row0 + r0, g1 = row0 + r1;
    if (g0 < n) {
        #pragma unroll
        for (int q = 0; q < 4; ++q)
            ((float4*)io)[((size_t)g0 * DD + cb + (q << 2)) >> 2] =
                make_float4(a0[q*4+0], a0[q*4+1], a0[q*4+2], a0[q*4+3]);
    }
    if (g1 < n) {
        #pragma unroll
        for (int q = 0; q < 4; ++q)
            ((float4*)io)[((size_t)g1 * DD + cb + (q << 2)) >> 2] =
                make_float4(a1[q*4+0], a1[q*4+1], a1[q*4+2], a1[q*4+3]);
    }
}

extern "C" void kernel_launch(void* const* d_in, const int* in_sizes, int n_in,
                              void* d_out, int out_size, void* d_ws, size_t ws_size,
                              hipStream_t stream)
{
    const float* x    = (const float*)d_in[0];
    const int*   esrc = (const int*)d_in[1];
    const int*   edst = (const int*)d_in[2];
    const float* w1   = (const float*)d_in[3];
    const float* b1   = (const float*)d_in[4];
    const float* w2   = (const float*)d_in[5];
    const float* b2   = (const float*)d_in[6];
    float* out = (float*)d_out;

    int N = in_sizes[0] / DD;   // 50000
    int E = in_sizes[1];        // 800000
    int nb = (N + 255) / 256;   // 196

    // workspace layout (all in d_ws, 256 MB)
    int*            offs       = (int*)d_ws;                         // N
    float*          rs_odeg    = (float*)(offs + N);                 // N
    float*          rs_ideg    = rs_odeg + N;                        // N
    int*            bsum       = (int*)(rs_ideg + N);                // 256
    int*            sorted_src = bsum + 256;                         // E
    unsigned short* hist_o     = (unsigned short*)(sorted_src + E);  // NSLICE*N
    unsigned short* hist_i     = hist_o + (size_t)NSLICE * N;        // NSLICE*N

    hist_kernel<<<dim3(NSLICE, NSEG), 256, 0, stream>>>(esrc, edst, hist_o, hist_i, E, N);
    reduce_scan_kernel<<<nb, 256, 0, stream>>>(hist_o, hist_i, offs, rs_odeg, rs_ideg, bsum, N);
    scan_add_kernel<<<nb, 256, 0, stream>>>(offs, bsum, N);
    bucket_kernel<<<dim3(NSLICE, NSEG), 256, 0, stream>>>(esrc, edst, offs, hist_i, sorted_src, E, N);
    gather_kernel<<<(N + 3) / 4, 256, 0, stream>>>(x, sorted_src, offs, rs_odeg, rs_ideg, out, N, E);
    ffn_kernel<<<(N + 63) / 64, 128, 0, stream>>>(out, w1, b1, w2, b2, N);
}

// Round 9
// 179.003 us; speedup vs baseline: 1.1679x; 1.0200x over previous
//
#include <hip/hip_runtime.h>
#include <hip/hip_bf16.h>
#include <math.h>

#define DD 64
#define NSLICE 64          // edge slices; per-slice edges = 12500 (<2^15, u16-safe)
#define SEG 16768          // nodes per segment; 3 segments cover N=50000
#define NSEG 3

__device__ __forceinline__ int wave_incl_scan(int v, int lane) {
    #pragma unroll
    for (int d = 1; d < 64; d <<= 1) {
        int u = __shfl_up(v, d, 64);
        if (lane >= d) v += u;
    }
    return v;
}

// ---------------- histogram: grid = (slice, segment), packed u16 LDS ------
__global__ __launch_bounds__(256) void hist_kernel(
    const int* __restrict__ src, const int* __restrict__ dst,
    unsigned short* __restrict__ hist_o, unsigned short* __restrict__ hist_i,
    int E, int N)
{
    __shared__ unsigned int ho[SEG / 2];
    __shared__ unsigned int hi[SEG / 2];
    int b = blockIdx.x, s = blockIdx.y, t = threadIdx.x;
    int per = (E + NSLICE - 1) / NSLICE;
    int e0 = b * per, e1 = min(E, e0 + per);
    int base = s * SEG;
    int segn = min(SEG, N - base);
    if (segn <= 0) return;

    for (int j = t; j < SEG / 2; j += 256) { ho[j] = 0u; hi[j] = 0u; }
    __syncthreads();

    int eV = e1 & ~3;
    const int4* s4 = (const int4*)src;
    const int4* d4 = (const int4*)dst;
    for (int q = (e0 >> 2) + t; q < (eV >> 2); q += 256) {
        int4 sv = s4[q];
        int4 dv = d4[q];
        unsigned u;
        u = (unsigned)(sv.x - base); if (u < (unsigned)segn) atomicAdd(&ho[u >> 1], 1u << ((u & 1) * 16));
        u = (unsigned)(sv.y - base); if (u < (unsigned)segn) atomicAdd(&ho[u >> 1], 1u << ((u & 1) * 16));
        u = (unsigned)(sv.z - base); if (u < (unsigned)segn) atomicAdd(&ho[u >> 1], 1u << ((u & 1) * 16));
        u = (unsigned)(sv.w - base); if (u < (unsigned)segn) atomicAdd(&ho[u >> 1], 1u << ((u & 1) * 16));
        u = (unsigned)(dv.x - base); if (u < (unsigned)segn) atomicAdd(&hi[u >> 1], 1u << ((u & 1) * 16));
        u = (unsigned)(dv.y - base); if (u < (unsigned)segn) atomicAdd(&hi[u >> 1], 1u << ((u & 1) * 16));
        u = (unsigned)(dv.z - base); if (u < (unsigned)segn) atomicAdd(&hi[u >> 1], 1u << ((u & 1) * 16));
        u = (unsigned)(dv.w - base); if (u < (unsigned)segn) atomicAdd(&hi[u >> 1], 1u << ((u & 1) * 16));
    }
    for (int e = eV + t; e < e1; e += 256) {
        unsigned u;
        u = (unsigned)(src[e] - base); if (u < (unsigned)segn) atomicAdd(&ho[u >> 1], 1u << ((u & 1) * 16));
        u = (unsigned)(dst[e] - base); if (u < (unsigned)segn) atomicAdd(&hi[u >> 1], 1u << ((u & 1) * 16));
    }
    __syncthreads();
    for (int j = t; j < segn; j += 256) {
        unsigned sh = (j & 1) * 16;
        hist_o[(size_t)b * N + base + j] = (unsigned short)((ho[j >> 1] >> sh) & 0xFFFFu);
        hist_i[(size_t)b * N + base + j] = (unsigned short)((hi[j >> 1] >> sh) & 0xFFFFu);
    }
}

// ------ fused reduce + block-level scan ------
__global__ __launch_bounds__(256) void reduce_scan_kernel(
    const unsigned short* __restrict__ hist_o, unsigned short* __restrict__ hist_i,
    int* __restrict__ offs, float* __restrict__ rs_odeg,
    float* __restrict__ rs_ideg, int* __restrict__ bsum, int N)
{
    int t = threadIdx.x, lane = t & 63, wid = t >> 6;
    int d = blockIdx.x * 256 + t;
    int run_o = 0, run_i = 0;
    if (d < N) {
        #pragma unroll 4
        for (int b = 0; b < NSLICE; ++b) {
            run_o += hist_o[(size_t)b * N + d];
            int tv = hist_i[(size_t)b * N + d];
            hist_i[(size_t)b * N + d] = (unsigned short)run_i;  // excl prefix over slices
            run_i += tv;
        }
    }
    int sv = wave_incl_scan(run_i, lane);
    __shared__ int ws[4], wso[4];
    if (lane == 63) ws[wid] = sv;
    __syncthreads();
    if (t == 0) {
        int a = 0;
        for (int w = 0; w < 4; ++w) { wso[w] = a; a += ws[w]; }
        bsum[blockIdx.x] = a;
    }
    __syncthreads();
    if (d < N) {
        offs[d] = sv - run_i + wso[wid];
        rs_odeg[d] = rsqrtf((float)run_o);   // inf only for never-src (never read)
        rs_ideg[d] = (run_i > 0) ? rsqrtf((float)run_i) : 0.0f;
    }
}

// ------ scan_add ------
__global__ __launch_bounds__(256) void scan_add_kernel(
    int* __restrict__ offs, const int* __restrict__ bsum, int n)
{
    __shared__ int wsum[4];
    int t = threadIdx.x, lane = t & 63, wid = t >> 6;
    int v = (t < blockIdx.x) ? bsum[t] : 0;    // nb <= 256
    #pragma unroll
    for (int dlt = 32; dlt >= 1; dlt >>= 1) v += __shfl_xor(v, dlt, 64);
    if (lane == 0) wsum[wid] = v;
    __syncthreads();
    int pre = wsum[0] + wsum[1] + wsum[2] + wsum[3];
    int i = blockIdx.x * 256 + t;
    if (i < n) offs[i] += pre;
}

// ---- bucket fill: writes (src, weight) pairs; grid = (slice, segment) ----
__global__ __launch_bounds__(256) void bucket_kernel(
    const int* __restrict__ src, const int* __restrict__ dst,
    const int* __restrict__ offs, const unsigned short* __restrict__ hist_i,
    const float* __restrict__ rs_odeg,
    int2* __restrict__ sorted_sw, int E, int N)
{
    __shared__ int cur[SEG];
    int b = blockIdx.x, s = blockIdx.y, t = threadIdx.x;
    int per = (E + NSLICE - 1) / NSLICE;
    int e0 = b * per, e1 = min(E, e0 + per);
    int base = s * SEG;
    int segn = min(SEG, N - base);
    if (segn <= 0) return;

    for (int j = t; j < segn; j += 256)
        cur[j] = offs[base + j] + (int)hist_i[(size_t)b * N + base + j];
    __syncthreads();

    int eV = e1 & ~3;
    const int4* s4 = (const int4*)src;
    const int4* d4 = (const int4*)dst;
    for (int q = (e0 >> 2) + t; q < (eV >> 2); q += 256) {
        int4 dv = d4[q];
        int4 sv = s4[q];
        unsigned ux = (unsigned)(dv.x - base);
        unsigned uy = (unsigned)(dv.y - base);
        unsigned uz = (unsigned)(dv.z - base);
        unsigned uw = (unsigned)(dv.w - base);
        // issue the (cached, 200 KB) weight reads early, independent
        float wx = (ux < (unsigned)segn) ? rs_odeg[sv.x] : 0.0f;
        float wy = (uy < (unsigned)segn) ? rs_odeg[sv.y] : 0.0f;
        float wz = (uz < (unsigned)segn) ? rs_odeg[sv.z] : 0.0f;
        float ww = (uw < (unsigned)segn) ? rs_odeg[sv.w] : 0.0f;
        if (ux < (unsigned)segn) sorted_sw[atomicAdd(&cur[ux], 1)] = make_int2(sv.x, __float_as_int(wx));
        if (uy < (unsigned)segn) sorted_sw[atomicAdd(&cur[uy], 1)] = make_int2(sv.y, __float_as_int(wy));
        if (uz < (unsigned)segn) sorted_sw[atomicAdd(&cur[uz], 1)] = make_int2(sv.z, __float_as_int(wz));
        if (uw < (unsigned)segn) sorted_sw[atomicAdd(&cur[uw], 1)] = make_int2(sv.w, __float_as_int(ww));
    }
    for (int e = eV + t; e < e1; e += 256) {
        unsigned u = (unsigned)(dst[e] - base);
        if (u < (unsigned)segn) {
            int sv = src[e];
            sorted_sw[atomicAdd(&cur[u], 1)] = make_int2(sv, __float_as_int(rs_odeg[sv]));
        }
    }
}

// ---------------- gather: wave per node, 16-edge unroll (4 loads deep) ----
__global__ __launch_bounds__(256) void gather_kernel(
    const float* __restrict__ x,
    const int2* __restrict__ sorted_sw,
    const int* __restrict__ offs,
    const float* __restrict__ rs_ideg,
    float* __restrict__ out, int N, int E)
{
    __shared__ int   sS[4][68];
    __shared__ float sW[4][68];
    int t = threadIdx.x, lane = t & 63, wid = t >> 6;
    int sub = lane >> 4, c4 = lane & 15;
    int d = blockIdx.x * 4 + wid;
    if (d >= N) return;

    int beg = offs[d];
    int end = (d + 1 < N) ? offs[d + 1] : E;
    int cnt = end - beg;
    int capped = min(cnt, 64);

    int s_l = 0; float w_l = 0.0f;
    if (lane < capped) {
        int2 p = sorted_sw[beg + lane];
        s_l = p.x;
        w_l = __int_as_float(p.y);
    }
    sS[wid][lane] = s_l;
    sW[wid][lane] = w_l;
    if (lane < 4) { sS[wid][64 + lane] = 0; sW[wid][64 + lane] = 0.0f; }

    float4 acc = make_float4(0.f, 0.f, 0.f, 0.f);
    int j = 0;
    for (; j + 16 <= capped; j += 16) {
        int j0 = j + sub, j1 = j + 4 + sub, j2 = j + 8 + sub, j3 = j + 12 + sub;
        int   sA = sS[wid][j0], sB = sS[wid][j1], sC = sS[wid][j2], sD = sS[wid][j3];
        float wA = sW[wid][j0], wB = sW[wid][j1], wC = sW[wid][j2], wD = sW[wid][j3];
        const float4 xa = *(const float4*)&x[(size_t)sA * DD + (c4 << 2)];
        const float4 xb = *(const float4*)&x[(size_t)sB * DD + (c4 << 2)];
        const float4 xc = *(const float4*)&x[(size_t)sC * DD + (c4 << 2)];
        const float4 xd = *(const float4*)&x[(size_t)sD * DD + (c4 << 2)];
        acc.x = fmaf(wA, xa.x, acc.x); acc.y = fmaf(wA, xa.y, acc.y);
        acc.z = fmaf(wA, xa.z, acc.z); acc.w = fmaf(wA, xa.w, acc.w);
        acc.x = fmaf(wB, xb.x, acc.x); acc.y = fmaf(wB, xb.y, acc.y);
        acc.z = fmaf(wB, xb.z, acc.z); acc.w = fmaf(wB, xb.w, acc.w);
        acc.x = fmaf(wC, xc.x, acc.x); acc.y = fmaf(wC, xc.y, acc.y);
        acc.z = fmaf(wC, xc.z, acc.z); acc.w = fmaf(wC, xc.w, acc.w);
        acc.x = fmaf(wD, xd.x, acc.x); acc.y = fmaf(wD, xd.y, acc.y);
        acc.z = fmaf(wD, xd.z, acc.z); acc.w = fmaf(wD, xd.w, acc.w);
    }
    for (; j + 8 <= capped; j += 8) {
        int j0 = j + sub, j1 = j + 4 + sub;
        int   sA = sS[wid][j0], sB = sS[wid][j1];
        float wA = sW[wid][j0], wB = sW[wid][j1];
        const float4 xa = *(const float4*)&x[(size_t)sA * DD + (c4 << 2)];
        const float4 xb = *(const float4*)&x[(size_t)sB * DD + (c4 << 2)];
        acc.x = fmaf(wA, xa.x, acc.x); acc.y = fmaf(wA, xa.y, acc.y);
        acc.z = fmaf(wA, xa.z, acc.z); acc.w = fmaf(wA, xa.w, acc.w);
        acc.x = fmaf(wB, xb.x, acc.x); acc.y = fmaf(wB, xb.y, acc.y);
        acc.z = fmaf(wB, xb.z, acc.z); acc.w = fmaf(wB, xb.w, acc.w);
    }
    for (; j < capped; j += 4) {
        int jj = j + sub;                 // pads [64..67] are zero-weight
        int   s = sS[wid][jj];
        float w = sW[wid][jj];
        const float4 xv = *(const float4*)&x[(size_t)s * DD + (c4 << 2)];
        acc.x = fmaf(w, xv.x, acc.x); acc.y = fmaf(w, xv.y, acc.y);
        acc.z = fmaf(w, xv.z, acc.z); acc.w = fmaf(w, xv.w, acc.w);
    }
    for (int jt = 64 + sub; jt < cnt; jt += 4) {   // rare: degree > 64
        int2 p = sorted_sw[beg + jt];
        float w = __int_as_float(p.y);
        const float4 xv = *(const float4*)&x[(size_t)p.x * DD + (c4 << 2)];
        acc.x = fmaf(w, xv.x, acc.x); acc.y = fmaf(w, xv.y, acc.y);
        acc.z = fmaf(w, xv.z, acc.z); acc.w = fmaf(w, xv.w, acc.w);
    }
    acc.x += __shfl_xor(acc.x, 16, 64); acc.x += __shfl_xor(acc.x, 32, 64);
    acc.y += __shfl_xor(acc.y, 16, 64); acc.y += __shfl_xor(acc.y, 32, 64);
    acc.z += __shfl_xor(acc.z, 16, 64); acc.z += __shfl_xor(acc.z, 32, 64);
    acc.w += __shfl_xor(acc.w, 16, 64); acc.w += __shfl_xor(acc.w, 32, 64);

    float nd = rs_ideg[d];
    if (sub == 0) {
        acc.x *= nd; acc.y *= nd; acc.z *= nd; acc.w *= nd;
        *(float4*)&out[(size_t)d * DD + (c4 << 2)] = acc;
    }
}

// ---- FFN: block=128, 128 rows, 4 rows/thread, LDS weights ----
// thread t: col chunk cb=(t&3)*16, rows slot+32i (slot=t>>2, i=0..3).
// Per k: 4 b32 + 4 b128 LDS issues feed 64 FMAs.
__global__ __launch_bounds__(128) void ffn_kernel(
    float* __restrict__ io,
    const float* __restrict__ w1, const float* __restrict__ b1,
    const float* __restrict__ w2, const float* __restrict__ b2, int n)
{
    __shared__ float sW1[4096];
    __shared__ float sW2[4096];
    __shared__ float sT[128 * 68];

    int t = threadIdx.x;
    int row0 = blockIdx.x * 128;

    const float4* w1v = (const float4*)w1;
    const float4* w2v = (const float4*)w2;
    #pragma unroll
    for (int q = 0; q < 8; ++q) {
        ((float4*)sW1)[t + q * 128] = w1v[t + q * 128];
        ((float4*)sW2)[t + q * 128] = w2v[t + q * 128];
    }
    #pragma unroll
    for (int q = 0; q < 16; ++q) {
        int idx4 = t + q * 128;          // float4 index in 128x64 tile
        int r = idx4 >> 4;
        int c = (idx4 & 15) << 2;
        int gr = row0 + r;
        float4 v = (gr < n) ? ((const float4*)io)[((size_t)gr * DD + c) >> 2]
                            : make_float4(0.f, 0.f, 0.f, 0.f);
        *(float4*)&sT[r * 68 + c] = v;
    }
    __syncthreads();

    int slot = t >> 2;            // 0..31
    int cb = (t & 3) << 4;

    float a[4][16];
    #pragma unroll
    for (int j = 0; j < 16; ++j) {
        float bv = b1[cb + j];
        a[0][j] = bv; a[1][j] = bv; a[2][j] = bv; a[3][j] = bv;
    }
    #pragma unroll 2
    for (int k = 0; k < 64; ++k) {
        float rv0 = sT[(slot      ) * 68 + k];
        float rv1 = sT[(slot + 32 ) * 68 + k];
        float rv2 = sT[(slot + 64 ) * 68 + k];
        float rv3 = sT[(slot + 96 ) * 68 + k];
        #pragma unroll
        for (int q = 0; q < 4; ++q) {
            float4 w = *(const float4*)&sW1[k * 64 + cb + (q << 2)];
            a[0][q*4+0] = fmaf(rv0, w.x, a[0][q*4+0]); a[1][q*4+0] = fmaf(rv1, w.x, a[1][q*4+0]);
            a[2][q*4+0] = fmaf(rv2, w.x, a[2][q*4+0]); a[3][q*4+0] = fmaf(rv3, w.x, a[3][q*4+0]);
            a[0][q*4+1] = fmaf(rv0, w.y, a[0][q*4+1]); a[1][q*4+1] = fmaf(rv1, w.y, a[1][q*4+1]);
            a[2][q*4+1] = fmaf(rv2, w.y, a[2][q*4+1]); a[3][q*4+1] = fmaf(rv3, w.y, a[3][q*4+1]);
            a[0][q*4+2] = fmaf(rv0, w.z, a[0][q*4+2]); a[1][q*4+2] = fmaf(rv1, w.z, a[1][q*4+2]);
            a[2][q*4+2] = fmaf(rv2, w.z, a[2][q*4+2]); a[3][q*4+2] = fmaf(rv3, w.z, a[3][q*4+2]);
            a[0][q*4+3] = fmaf(rv0, w.w, a[0][q*4+3]); a[1][q*4+3] = fmaf(rv1, w.w, a[1][q*4+3]);
            a[2][q*4+3] = fmaf(rv2, w.w, a[2][q*4+3]); a[3][q*4+3] = fmaf(rv3, w.w, a[3][q*4+3]);
        }
    }
    #pragma unroll
    for (int i = 0; i < 4; ++i)
        #pragma unroll
        for (int j = 0; j < 16; ++j) {
            float v = a[i][j];
            a[i][j] = 0.5f * v * (1.0f + erff(v * 0.70710678118654752f));
        }
    __syncthreads();   // all GEMM1 reads of sT complete before overwrite
    #pragma unroll
    for (int i = 0; i < 4; ++i)
        #pragma unroll
        for (int q = 0; q < 4; ++q)
            *(float4*)&sT[(slot + 32 * i) * 68 + cb + (q << 2)] =
                make_float4(a[i][q*4+0], a[i][q*4+1], a[i][q*4+2], a[i][q*4+3]);
    __syncthreads();

    float o[4][16];
    #pragma unroll
    for (int j = 0; j < 16; ++j) {
        float bv = b2[cb + j];
        o[0][j] = bv; o[1][j] = bv; o[2][j] = bv; o[3][j] = bv;
    }
    #pragma unroll 2
    for (int k = 0; k < 64; ++k) {
        float hv0 = sT[(slot      ) * 68 + k];
        float hv1 = sT[(slot + 32 ) * 68 + k];
        float hv2 = sT[(slot + 64 ) * 68 + k];
        float hv3 = sT[(slot + 96 ) * 68 + k];
        #pragma unroll
        for (int q = 0; q < 4; ++q) {
            float4 w = *(const float4*)&sW2[k * 64 + cb + (q << 2)];
            o[0][q*4+0] = fmaf(hv0, w.x, o[0][q*4+0]); o[1][q*4+0] = fmaf(hv1, w.x, o[1][q*4+0]);
            o[2][q*4+0] = fmaf(hv2, w.x, o[2][q*4+0]); o[3][q*4+0] = fmaf(hv3, w.x, o[3][q*4+0]);
            o[0][q*4+1] = fmaf(hv0, w.y, o[0][q*4+1]); o[1][q*4+1] = fmaf(hv1, w.y, o[1][q*4+1]);
            o[2][q*4+1] = fmaf(hv2, w.y, o[2][q*4+1]); o[3][q*4+1] = fmaf(hv3, w.y, o[3][q*4+1]);
            o[0][q*4+2] = fmaf(hv0, w.z, o[0][q*4+2]); o[1][q*4+2] = fmaf(hv1, w.z, o[1][q*4+2]);
            o[2][q*4+2] = fmaf(hv2, w.z, o[2][q*4+2]); o[3][q*4+2] = fmaf(hv3, w.z, o[3][q*4+2]);
            o[0][q*4+3] = fmaf(hv0, w.w, o[0][q*4+3]); o[1][q*4+3] = fmaf(hv1, w.w, o[1][q*4+3]);
            o[2][q*4+3] = fmaf(hv2, w.w, o[2][q*4+3]); o[3][q*4+3] = fmaf(hv3, w.w, o[3][q*4+3]);
        }
    }
    __syncthreads();   // all GEMM2 reads done before overwrite
    #pragma unroll
    for (int i = 0; i < 4; ++i)
        #pragma unroll
        for (int q = 0; q < 4; ++q)
            *(float4*)&sT[(slot + 32 * i) * 68 + cb + (q << 2)] =
                make_float4(o[i][q*4+0], o[i][q*4+1], o[i][q*4+2], o[i][q*4+3]);
    __syncthreads();
    // coalesced store
    #pragma unroll
    for (int q = 0; q < 16; ++q) {
        int idx4 = t + q * 128;
        int r = idx4 >> 4;
        int c = (idx4 & 15) << 2;
        int gr = row0 + r;
        if (gr < n)
            ((float4*)io)[((size_t)gr * DD + c) >> 2] = *(const float4*)&sT[r * 68 + c];
    }
}

extern "C" void kernel_launch(void* const* d_in, const int* in_sizes, int n_in,
                              void* d_out, int out_size, void* d_ws, size_t ws_size,
                              hipStream_t stream)
{
    const float* x    = (const float*)d_in[0];
    const int*   esrc = (const int*)d_in[1];
    const int*   edst = (const int*)d_in[2];
    const float* w1   = (const float*)d_in[3];
    const float* b1   = (const float*)d_in[4];
    const float* w2   = (const float*)d_in[5];
    const float* b2   = (const float*)d_in[6];
    float* out = (float*)d_out;

    int N = in_sizes[0] / DD;   // 50000
    int E = in_sizes[1];        // 800000
    int nb = (N + 255) / 256;   // 196

    // workspace layout (d_ws, 8B-aligned base): pairs first for int2 alignment
    int2*           sorted_sw  = (int2*)d_ws;                        // E
    int*            offs       = (int*)(sorted_sw + E);              // N
    float*          rs_odeg    = (float*)(offs + N);                 // N
    float*          rs_ideg    = rs_odeg + N;                        // N
    int*            bsum       = (int*)(rs_ideg + N);                // 256
    unsigned short* hist_o     = (unsigned short*)(bsum + 256);      // NSLICE*N
    unsigned short* hist_i     = hist_o + (size_t)NSLICE * N;        // NSLICE*N

    hist_kernel<<<dim3(NSLICE, NSEG), 256, 0, stream>>>(esrc, edst, hist_o, hist_i, E, N);
    reduce_scan_kernel<<<nb, 256, 0, stream>>>(hist_o, hist_i, offs, rs_odeg, rs_ideg, bsum, N);
    scan_add_kernel<<<nb, 256, 0, stream>>>(offs, bsum, N);
    bucket_kernel<<<dim3(NSLICE, NSEG), 256, 0, stream>>>(esrc, edst, offs, hist_i, rs_odeg, sorted_sw, E, N);
    gather_kernel<<<(N + 3) / 4, 256, 0, stream>>>(x, sorted_sw, offs, rs_ideg, out, N, E);
    ffn_kernel<<<(N + 127) / 128, 128, 0, stream>>>(out, w1, b1, w2, b2, N);
}